// Round 12
// baseline (280.428 us; speedup 1.0000x reference)
//
#include <hip/hip_runtime.h>
#include <hip/hip_bf16.h>
#include <hip/hip_cooperative_groups.h>
namespace cg = cooperative_groups;

typedef unsigned short u16;
typedef __bf16 bf16x8 __attribute__((ext_vector_type(8)));
typedef __bf16 bf16x4 __attribute__((ext_vector_type(4)));
typedef float f32x4 __attribute__((ext_vector_type(4)));
typedef unsigned short u16x8 __attribute__((ext_vector_type(8)));

// round-to-nearest-even fp32 -> bf16 (epilogue paths only)
__device__ inline u16 f2bf(float f) {
    union { float f; unsigned u; } v; v.f = f;
    unsigned r = v.u + 0x7fffu + ((v.u >> 16) & 1u);
    return (u16)(r >> 16);
}

// ---------------------------------------------------------------------------
// Convert x and 4 weights to bf16, contiguous in ws:
//   [x_bf 4194304][wq 1048576][wk][wv][wo]
// (FALLBACK path only — the cooperative fused kernel below does this inline.)
// ---------------------------------------------------------------------------
__global__ void convert_kernel(const float* __restrict__ x,
                               const float* __restrict__ wq, const float* __restrict__ wk,
                               const float* __restrict__ wv, const float* __restrict__ wo,
                               u16* __restrict__ dst) {
    long g = (long)blockIdx.x * blockDim.x + threadIdx.x;  // group of 4 elements
    const float* src; long base;
    const long GX = 1048576, GW = 262144;
    if (g < GX)            { src = x;  base = 0; }
    else if (g < GX + GW)  { src = wq; base = GX; }
    else if (g < GX + 2*GW){ src = wk; base = GX + GW; }
    else if (g < GX + 3*GW){ src = wv; base = GX + 2*GW; }
    else                   { src = wo; base = GX + 3*GW; }
    long rel = g - base;
    float4 v = reinterpret_cast<const float4*>(src)[rel];
    ushort4 o;
    o.x = f2bf(v.x); o.y = f2bf(v.y); o.z = f2bf(v.z); o.w = f2bf(v.w);
    reinterpret_cast<ushort4*>(dst)[g] = o;
}

// ---------------------------------------------------------------------------
// QKV compute body (R10-verbatim, factored so the cooperative fused kernel
// and the fallback kernel share code). Z-FUSED: one block computes q, k AND
// v for its (t0, n0) tile; A staged once feeds 3 W-tiles. Grid (32,8) =
// 256 blocks = 1 block/CU, 8 waves, LDS 128 KB. Natural-order grid (R7
// lesson: do NOT XCD-swizzle; round-robin already pins A-tiles per XCD).
// R11's LDS-transpose epilogue was null (+1.2); R10 scalar epilogue kept.
//   q_ws/k_ws: [bh][s][64] bf16 (q pre-scaled by log2(e)/8)
//   v_ws:      [bh][64][s] bf16 (transposed for attention PV B-frags)
// ---------------------------------------------------------------------------
__device__ __forceinline__ void qkv_compute(
    const u16* __restrict__ x_bf,
    const u16* __restrict__ wq, const u16* __restrict__ wk, const u16* __restrict__ wv,
    const float* __restrict__ sq, const float* __restrict__ sk, const float* __restrict__ sv,
    const float* __restrict__ bq, const float* __restrict__ bk, const float* __restrict__ bv,
    u16* __restrict__ q_ws, u16* __restrict__ k_ws, u16* __restrict__ v_ws,
    u16* As, u16* Bs)   // As: 2*8192 u16, Bs: 2*24576 u16
{
    const int t0 = blockIdx.x * 128, n0 = blockIdx.y * 128;
    const int tid = threadIdx.x;
    const int wid = tid >> 6, lane = tid & 63, quad = lane >> 4, ln = lane & 15;
    const int wm = wid >> 2, wn = wid & 3;   // 2x4 wave grid, wave tile 64x32 per z

    // staging assignment (wave-uniform): waves 0-1 stage A, waves 2-7 stage B
    const bool stA = (wid < 2);
    const int zz = stA ? 0 : ((wid - 2) >> 1);
    const u16* Wz = (zz == 0) ? wq : (zz == 1) ? wk : wv;
    const u16* gbase = stA ? x_bf : Wz;
    const int r0 = stA ? t0 : n0;
    const int ccb = stA ? (wid * 8) : (((wid - 2) & 1) * 8);  // chunk base 0 or 8

    // per-lane source geometry: chunk = 8 rows x 128 B; lane fills 16 B
    const int lrow = lane >> 3;                       // row within chunk (0..7)
    const int sel  = 8 * ((lane & 7) ^ lrow);         // swizzled src col (els)

    f32x4 acc[3][4][2];
#pragma unroll
    for (int z = 0; z < 3; z++)
#pragma unroll
        for (int im = 0; im < 4; im++)
#pragma unroll
            for (int in = 0; in < 2; in++) acc[z][im][in] = (f32x4){0.f, 0.f, 0.f, 0.f};

#define QK_STAGE(buf, k0)                                                             \
    {                                                                                 \
        u16* dbase = stA ? (As + (buf) * 8192) : (Bs + (buf) * 24576 + zz * 8192);    \
        _Pragma("unroll")                                                             \
        for (int i = 0; i < 8; i++) {                                                 \
            int cc = ccb + i;                                                         \
            const u16* g = gbase + (long)(r0 + cc * 8 + lrow) * 1024 + (k0) + sel;    \
            __builtin_amdgcn_global_load_lds(                                         \
                (const __attribute__((address_space(1))) void*)g,                     \
                (__attribute__((address_space(3))) void*)(dbase + cc * 512), 16, 0, 0); \
        }                                                                             \
    }

    QK_STAGE(0, 0);
    __syncthreads();

    int cur = 0;
    for (int k0 = 0; k0 < 1024; k0 += 64) {
        if (k0 + 64 < 1024) QK_STAGE(cur ^ 1, k0 + 64);
        const char* Ac = (const char*)(As + cur * 8192);
        const char* Bc = (const char*)(Bs + cur * 24576);
#pragma unroll
        for (int ks = 0; ks < 2; ks++) {
            bf16x8 af[4];
#pragma unroll
            for (int im = 0; im < 4; im++) {
                int r = wm * 64 + im * 16 + ln;
                int byt = (r * 128 + ks * 64 + quad * 16) ^ ((r & 7) << 4);
                af[im] = *reinterpret_cast<const bf16x8*>(Ac + byt);
            }
            int rb = wn * 32 + ln;
#pragma unroll
            for (int z = 0; z < 3; z++) {
                bf16x8 b0, b1;
                {
                    int r = rb;
                    int byt = (r * 128 + ks * 64 + quad * 16) ^ ((r & 7) << 4);
                    b0 = *reinterpret_cast<const bf16x8*>(Bc + z * 16384 + byt);
                    r = rb + 16;
                    byt = (r * 128 + ks * 64 + quad * 16) ^ ((r & 7) << 4);
                    b1 = *reinterpret_cast<const bf16x8*>(Bc + z * 16384 + byt);
                }
                __builtin_amdgcn_s_setprio(1);
#pragma unroll
                for (int im = 0; im < 4; im++) {
                    acc[z][im][0] = __builtin_amdgcn_mfma_f32_16x16x32_bf16(af[im], b0, acc[z][im][0], 0, 0, 0);
                    acc[z][im][1] = __builtin_amdgcn_mfma_f32_16x16x32_bf16(af[im], b1, acc[z][im][1], 0, 0, 0);
                }
                __builtin_amdgcn_s_setprio(0);
            }
        }
        // single barrier: (a) protects buf[cur] reuse, (b) drains DMA into buf^1
        __syncthreads();
        cur ^= 1;
    }
#undef QK_STAGE

    // epilogue (R10 scalar form — measured best)
    const float sq_ = sq[0] * 0.125f * 1.44269504088896f;  // softmax scale + log2e
    const float sk_ = sk[0];
    const float sv_ = sv[0];
#pragma unroll
    for (int z = 0; z < 3; z++) {
        u16* dst = (z == 0) ? q_ws : (z == 1) ? k_ws : v_ws;
        const float* bp = (z == 0) ? bq : (z == 1) ? bk : bv;
        const float s = (z == 0) ? sq_ : (z == 1) ? sk_ : sv_;
        const float be = (z == 0) ? 0.125f * 1.44269504088896f : 1.0f;
#pragma unroll
        for (int in = 0; in < 2; in++) {
            int col = n0 + wn * 32 + in * 16 + ln;
            float bias = bp[col] * be;
            int h = col >> 6, d = col & 63;
#pragma unroll
            for (int im = 0; im < 4; im++) {
                int rbase = t0 + wm * 64 + im * 16 + quad * 4;
#pragma unroll
                for (int j2 = 0; j2 < 4; j2++) {
                    int t = rbase + j2;
                    int b = t >> 11, ss = t & 2047;
                    int bh = b * 16 + h;
                    float val = acc[z][im][in][j2] * s + bias;
                    long idx = (z < 2) ? ((long)(bh * 2048 + ss) * 64 + d)
                                       : ((long)(bh * 64 + d) * 2048 + ss);
                    dst[idx] = f2bf(val);
                }
            }
        }
    }
}

// ---------------------------------------------------------------------------
// R12: COOPERATIVE fused convert+qkv. Hypothesis under test: sum of per-
// dispatch durations (~77 us) is far below total (~186 us) -> ~27 us per
// launch of inter-dispatch overhead. Phase 1 converts all fp32 inputs to
// bf16 (grid-stride, 131072 threads, exactly 16 iters over 2.1M groups);
// grid.sync(); phase 2 = unchanged R10 qkv body. Work is relocated 1:1 —
// any total-time delta isolates the launch-gap mass.
// ---------------------------------------------------------------------------
__global__ void __launch_bounds__(512)
qkv_fused(const float* __restrict__ xf,
          const float* __restrict__ wqf, const float* __restrict__ wkf,
          const float* __restrict__ wvf, const float* __restrict__ wof,
          const float* __restrict__ sq, const float* __restrict__ sk, const float* __restrict__ sv,
          const float* __restrict__ bq, const float* __restrict__ bk, const float* __restrict__ bv,
          u16* __restrict__ ws, u16* __restrict__ q_ws, u16* __restrict__ k_ws,
          u16* __restrict__ v_ws) {
    __shared__ __align__(16) u16 As[2 * 8192];
    __shared__ __align__(16) u16 Bs[2 * 24576];

    // ---- phase 1: bf16 conversion (grid-stride over 2,097,152 groups) ----
    {
        long g0 = (long)(blockIdx.x + 32 * blockIdx.y) * 512 + threadIdx.x;
#pragma unroll 1
        for (long g = g0; g < 2097152; g += 131072) {
            const float* src; long base;
            if (g < 1048576)      { src = xf;  base = 0; }
            else if (g < 1310720) { src = wqf; base = 1048576; }
            else if (g < 1572864) { src = wkf; base = 1310720; }
            else if (g < 1835008) { src = wvf; base = 1572864; }
            else                  { src = wof; base = 1835008; }
            float4 v = reinterpret_cast<const float4*>(src)[g - base];
            ushort4 o;
            o.x = f2bf(v.x); o.y = f2bf(v.y); o.z = f2bf(v.z); o.w = f2bf(v.w);
            reinterpret_cast<ushort4*>(ws)[g] = o;
        }
    }
    __threadfence();           // device-scope visibility across XCD L2s
    cg::this_grid().sync();

    // ---- phase 2: z-fused qkv GEMM (R10-verbatim) ----
    const u16* x_bf  = ws;
    const u16* wq_bf = ws + 4194304;
    const u16* wk_bf = wq_bf + 1048576;
    const u16* wv_bf = wk_bf + 1048576;
    qkv_compute(x_bf, wq_bf, wk_bf, wv_bf, sq, sk, sv, bq, bk, bv,
                q_ws, k_ws, v_ws, As, Bs);
}

// Fallback (non-cooperative) qkv — identical compute, used only if the
// cooperative launch is rejected at runtime.
__global__ void __launch_bounds__(512)
qkv_gemm(const u16* __restrict__ x_bf,
         const u16* __restrict__ wq, const u16* __restrict__ wk, const u16* __restrict__ wv,
         const float* __restrict__ sq, const float* __restrict__ sk, const float* __restrict__ sv,
         const float* __restrict__ bq, const float* __restrict__ bk, const float* __restrict__ bv,
         u16* __restrict__ q_ws, u16* __restrict__ k_ws, u16* __restrict__ v_ws) {
    __shared__ __align__(16) u16 As[2 * 8192];
    __shared__ __align__(16) u16 Bs[2 * 24576];
    qkv_compute(x_bf, wq, wk, wv, sq, sk, sv, bq, bk, bv, q_ws, k_ws, v_ws, As, Bs);
}

// ---------------------------------------------------------------------------
// Attention: per (q-tile of 128, bh). 512 threads = 8 waves, each wave owns
// 16 q-rows. (UNCHANGED — proven local optimum: 2 blocks/CU for barrier-
// convoy overlap; R9's 1-block/CU 256-row tile regressed.)
//
// XCD swizzle: XCD x pins 4 bh's K/V (2 MB, L2-resident), sweeps q-tiles
// (R7-measured: FETCH 69.7->12.3 MB). Schedule: DMA-before-compute into
// double-buffered swizzled-linear LDS, one barrier per K-tile; denominator
// on the MFMA pipe; swapped QK^T (S^T = mfma(K, Q)).
// ---------------------------------------------------------------------------
#define LDP 72

__global__ void __launch_bounds__(512)
attn_kernel(const u16* __restrict__ q_ws, const u16* __restrict__ k_ws,
            const u16* __restrict__ v_ws, u16* __restrict__ ctx) {
    __shared__ __align__(16) u16 Kb[2][4096];   // [buf][64 keys][64 d] swizzled
    __shared__ __align__(16) u16 Vb[2][4096];   // [buf][64 d][64 keys] swizzled
    __shared__ u16 Pt[128 * LDP];               // [q][key] exp(scores) bf16 (padded)

    const int tid = threadIdx.x;
    const int wid = tid >> 6, lane = tid & 63, quad = lane >> 4, ln = lane & 15;

    // XCD swizzle: XCD x pins 4 bh's K/V in its L2, sweeps q-tiles
    const int f   = blockIdx.x + 16 * blockIdx.y;
    const int xcd = f & 7, j = f >> 3;
    const int bh  = xcd * 4 + (j >> 4);
    const int q0  = (j & 15) * 128;

    const u16* qbase = q_ws + (long)bh * 2048 * 64;
    const u16* kbase = k_ws + (long)bh * 2048 * 64;
    const u16* vbase = v_ws + (long)bh * 64 * 2048;

    // staging geometry: wave w fills LDS bytes [w*1024 + lane*16)
    const int srow = wid * 8 + (lane >> 3);                  // tile row 0..63
    const int sel  = 8 * ((lane & 7) ^ ((lane >> 3) & 7));   // swizzled src col (els)
    // fragment-read XOR term (row ^= pattern depends only on ln&7)
    const int xr = (ln & 7) << 4;

    // Q fragments held in registers for the whole K loop
    bf16x8 aq[2];
#pragma unroll
    for (int ks = 0; ks < 2; ks++)
        aq[ks] = *reinterpret_cast<const bf16x8*>(
            qbase + (long)(q0 + wid * 16 + ln) * 64 + ks * 32 + quad * 8);

    // all-ones bf16 B-fragment for the denominator MFMA
    bf16x8 vones;
#pragma unroll
    for (int i = 0; i < 8; i++) vones[i] = (__bf16)1.0f;

    f32x4 acc_o[4];
    f32x4 acc_l = (f32x4){0.f, 0.f, 0.f, 0.f};
#pragma unroll
    for (int dt = 0; dt < 4; dt++) acc_o[dt] = (f32x4){0.f, 0.f, 0.f, 0.f};

    // incremental DMA source pointers (avoids per-iter 64-bit addr rebuild)
    const u16* kp = kbase + (long)srow * 64 + sel;     // advances by 64*64 els/tile
    const u16* vp = vbase + (long)srow * 2048 + sel;   // advances by 64 els/tile

    // prologue: stage tile 0 into buf 0
    __builtin_amdgcn_global_load_lds((const __attribute__((address_space(1))) void*)kp,
                                     (__attribute__((address_space(3))) void*)(&Kb[0][wid * 512]),
                                     16, 0, 0);
    __builtin_amdgcn_global_load_lds((const __attribute__((address_space(1))) void*)vp,
                                     (__attribute__((address_space(3))) void*)(&Vb[0][wid * 512]),
                                     16, 0, 0);
    kp += 4096; vp += 64;
    __syncthreads();

    int cur = 0;
    for (int kt = 0; kt < 2048; kt += 64) {
        // issue next tile's DMA first; it flies under this tile's compute
        if (kt + 64 < 2048) {
            __builtin_amdgcn_global_load_lds((const __attribute__((address_space(1))) void*)kp,
                                             (__attribute__((address_space(3))) void*)(&Kb[cur ^ 1][wid * 512]),
                                             16, 0, 0);
            __builtin_amdgcn_global_load_lds((const __attribute__((address_space(1))) void*)vp,
                                             (__attribute__((address_space(3))) void*)(&Vb[cur ^ 1][wid * 512]),
                                             16, 0, 0);
            kp += 4096; vp += 64;
        }
        const char* Kc = (const char*)(&Kb[cur][0]);
        const char* Vc = (const char*)(&Vb[cur][0]);

        // S^T = K Q^T (swapped). Lane (quad,ln): q = ln, keys = k8*16+quad*4+j
#pragma unroll
        for (int k8 = 0; k8 < 4; k8++) {
            bf16x8 a0 = *reinterpret_cast<const bf16x8*>(
                Kc + (k8 * 16 + ln) * 128 + ((quad * 16) ^ xr));
            bf16x8 a1 = *reinterpret_cast<const bf16x8*>(
                Kc + (k8 * 16 + ln) * 128 + ((64 + quad * 16) ^ xr));
            f32x4 t = (f32x4){0.f, 0.f, 0.f, 0.f};
            __builtin_amdgcn_s_setprio(1);
            t = __builtin_amdgcn_mfma_f32_16x16x32_bf16(a0, aq[0], t, 0, 0, 0);
            t = __builtin_amdgcn_mfma_f32_16x16x32_bf16(a1, aq[1], t, 0, 0, 0);
            __builtin_amdgcn_s_setprio(0);
            // bare v_exp_f32 (log2e folded into q); compiler-path bf16 casts
            __bf16 p0 = (__bf16)__builtin_amdgcn_exp2f(t[0]);
            __bf16 p1 = (__bf16)__builtin_amdgcn_exp2f(t[1]);
            __bf16 p2 = (__bf16)__builtin_amdgcn_exp2f(t[2]);
            __bf16 p3 = (__bf16)__builtin_amdgcn_exp2f(t[3]);
            *reinterpret_cast<bf16x4*>(Pt + (wid * 16 + ln) * LDP + k8 * 16 + quad * 4)
                = (bf16x4){p0, p1, p2, p3};
        }

        // O += P V ; l += P 1  (A-frag reads of Pt are wave-local rows)
#pragma unroll
        for (int step = 0; step < 2; step++) {
            bf16x8 ap = *reinterpret_cast<const bf16x8*>(
                Pt + (wid * 16 + ln) * LDP + step * 32 + quad * 8);
            bf16x8 bv0 = *reinterpret_cast<const bf16x8*>(
                Vc + (0 * 16 + ln) * 128 + ((step * 64 + quad * 16) ^ xr));
            bf16x8 bv1 = *reinterpret_cast<const bf16x8*>(
                Vc + (1 * 16 + ln) * 128 + ((step * 64 + quad * 16) ^ xr));
            bf16x8 bv2 = *reinterpret_cast<const bf16x8*>(
                Vc + (2 * 16 + ln) * 128 + ((step * 64 + quad * 16) ^ xr));
            bf16x8 bv3 = *reinterpret_cast<const bf16x8*>(
                Vc + (3 * 16 + ln) * 128 + ((step * 64 + quad * 16) ^ xr));
            __builtin_amdgcn_s_setprio(1);
            acc_o[0] = __builtin_amdgcn_mfma_f32_16x16x32_bf16(ap, bv0, acc_o[0], 0, 0, 0);
            acc_o[1] = __builtin_amdgcn_mfma_f32_16x16x32_bf16(ap, bv1, acc_o[1], 0, 0, 0);
            acc_o[2] = __builtin_amdgcn_mfma_f32_16x16x32_bf16(ap, bv2, acc_o[2], 0, 0, 0);
            acc_o[3] = __builtin_amdgcn_mfma_f32_16x16x32_bf16(ap, bv3, acc_o[3], 0, 0, 0);
            acc_l    = __builtin_amdgcn_mfma_f32_16x16x32_bf16(ap, vones, acc_l, 0, 0, 0);
            __builtin_amdgcn_s_setprio(0);
        }
        // single barrier per K-tile: orders (a) all reads of buf[cur] before it
        // is overwritten next iter, (b) drains this iter's DMA into buf[cur^1]
        __syncthreads();
        cur ^= 1;
    }

    // write ctx [t][h*64+d] bf16; acc_l[j] is the denominator for q-row
    // wid*16 + quad*4 + j (same row acc_o[dt][j] holds) — no shuffle needed
    const int b = bh >> 4, h = bh & 15;
#pragma unroll
    for (int j2 = 0; j2 < 4; j2++) {
        float rinv = 1.0f / acc_l[j2];
        int t = b * 2048 + q0 + wid * 16 + quad * 4 + j2;
#pragma unroll
        for (int dt = 0; dt < 4; dt++) {
            float val = acc_o[dt][j2] * rinv;
            ctx[(long)t * 1024 + h * 64 + dt * 16 + ln] = f2bf(val);
        }
    }
}

// ---------------------------------------------------------------------------
// Output projection: d_out[t][o] = ctx @ wo^T * s_o + b_o  (fp32 out)
// (UNCHANGED — natural-order grid, 8-wave double-buffered single-barrier.)
// ---------------------------------------------------------------------------
__global__ void __launch_bounds__(512)
o_gemm(const u16* __restrict__ ctx, const u16* __restrict__ wo,
       const float* __restrict__ so, const float* __restrict__ bo,
       float* __restrict__ out) {
    __shared__ __align__(16) u16 As[2][128 * 64];
    __shared__ __align__(16) u16 Bs[2][128 * 64];
    const int tid = threadIdx.x;
    const int wid = tid >> 6, lane = tid & 63, quad = lane >> 4, ln = lane & 15;
    const int wm = wid >> 2, wn = wid & 3;   // 2x4 wave grid, wave tile 64x32
    const int t0 = blockIdx.x * 128, n0 = blockIdx.y * 128;

    // wave-uniform staging assignment: waves 0-3 -> A chunks, 4-7 -> B chunks
    const bool stA = (wid < 4);
    const u16* gbase = stA ? ctx : wo;
    const int r0 = stA ? t0 : n0;
    const int cbase = (wid & 3) * 4;         // 4 chunks of 1 KB per wave

    f32x4 acc[4][2];
#pragma unroll
    for (int im = 0; im < 4; im++)
#pragma unroll
        for (int in = 0; in < 2; in++) acc[im][in] = (f32x4){0.f, 0.f, 0.f, 0.f};

    // per-lane staging source geometry (swizzled global source, linear LDS)
    const int sb   = cbase * 1024 + lane * 16;
    const int srow = sb >> 7;
    const int scb  = (sb & 127) ^ ((srow & 7) << 4);

#define O_STAGE(buf, k0)                                                              \
    {                                                                                 \
        const u16* g = gbase + (long)(r0 + srow) * 1024 + (k0) + (scb >> 1);          \
        u16* d = (stA ? &As[buf][0] : &Bs[buf][0]) + cbase * 512;                     \
        _Pragma("unroll")                                                             \
        for (int i = 0; i < 4; i++) {                                                 \
            __builtin_amdgcn_global_load_lds(                                         \
                (const __attribute__((address_space(1))) void*)(g + (long)i * 8 * 1024), \
                (__attribute__((address_space(3))) void*)(d + i * 512), 16, 0, 0);    \
        }                                                                             \
    }

    O_STAGE(0, 0);
    __syncthreads();

    int cur = 0;
    for (int k0 = 0; k0 < 1024; k0 += 64) {
        if (k0 + 64 < 1024) O_STAGE(cur ^ 1, k0 + 64);
        const char* Ac = (const char*)&As[cur][0];
        const char* Bc = (const char*)&Bs[cur][0];
#pragma unroll
        for (int ks = 0; ks < 2; ks++) {
            bf16x8 af[4], bfr[2];
#pragma unroll
            for (int im = 0; im < 4; im++) {
                int r = wm * 64 + im * 16 + ln;
                int byt = (r * 128 + ks * 64 + quad * 16) ^ ((r & 7) << 4);
                af[im] = *reinterpret_cast<const bf16x8*>(Ac + byt);
            }
#pragma unroll
            for (int in = 0; in < 2; in++) {
                int r = wn * 32 + in * 16 + ln;
                int byt = (r * 128 + ks * 64 + quad * 16) ^ ((r & 7) << 4);
                bfr[in] = *reinterpret_cast<const bf16x8*>(Bc + byt);
            }
#pragma unroll
            for (int im = 0; im < 4; im++)
#pragma unroll
                for (int in = 0; in < 2; in++)
                    acc[im][in] = __builtin_amdgcn_mfma_f32_16x16x32_bf16(af[im], bfr[in], acc[im][in], 0, 0, 0);
        }
        // single barrier: (a) protects buf[cur] reuse, (b) drains DMA into buf^1
        __syncthreads();
        cur ^= 1;
    }
#undef O_STAGE

    const float s = so[0];
#pragma unroll
    for (int in = 0; in < 2; in++) {
        int col = n0 + wn * 32 + in * 16 + ln;
        float bias = bo[col];
#pragma unroll
        for (int im = 0; im < 4; im++) {
            int rbase = t0 + wm * 64 + im * 16 + quad * 4;
#pragma unroll
            for (int j2 = 0; j2 < 4; j2++)
                out[(long)(rbase + j2) * 1024 + col] = acc[im][in][j2] * s + bias;
        }
    }
}

// ---------------------------------------------------------------------------
extern "C" void kernel_launch(void* const* d_in, const int* in_sizes, int n_in,
                              void* d_out, int out_size, void* d_ws, size_t ws_size,
                              hipStream_t stream) {
    const float* x   = (const float*)d_in[0];
    const float* w_q = (const float*)d_in[1];
    const float* s_q = (const float*)d_in[2];
    const float* b_q = (const float*)d_in[3];
    const float* w_k = (const float*)d_in[4];
    const float* s_k = (const float*)d_in[5];
    const float* b_k = (const float*)d_in[6];
    const float* w_v = (const float*)d_in[7];
    const float* s_v = (const float*)d_in[8];
    const float* b_v = (const float*)d_in[9];
    const float* w_o = (const float*)d_in[10];
    const float* s_o = (const float*)d_in[11];
    const float* b_o = (const float*)d_in[12];

    if (ws_size < (size_t)50331648) return;  // need 48 MB of scratch

    u16* ws     = (u16*)d_ws;
    u16* x_bf   = ws;                    // 4096*1024
    u16* wq_bf  = x_bf  + 4194304;       // 1024*1024 each
    u16* wk_bf  = wq_bf + 1048576;
    u16* wv_bf  = wk_bf + 1048576;
    u16* wo_bf  = wv_bf + 1048576;
    u16* q_ws   = wo_bf + 1048576;       // [32 bh][2048 s][64 d]
    u16* k_ws   = q_ws  + 4194304;
    u16* v_ws   = k_ws  + 4194304;       // [32 bh][64 d][2048 s]
    u16* ctx_ws = v_ws  + 4194304;       // [4096 t][1024]

    // cooperative fused convert+qkv (R12 gap-hypothesis test); graceful
    // fallback to the two-kernel R10 path if the coop launch is rejected.
    void* cargs[] = {(void*)&x, (void*)&w_q, (void*)&w_k, (void*)&w_v, (void*)&w_o,
                     (void*)&s_q, (void*)&s_k, (void*)&s_v,
                     (void*)&b_q, (void*)&b_k, (void*)&b_v,
                     (void*)&ws, (void*)&q_ws, (void*)&k_ws, (void*)&v_ws};
    hipError_t cerr = hipLaunchCooperativeKernel((const void*)qkv_fused,
                                                 dim3(32, 8), dim3(512),
                                                 cargs, 0, stream);
    if (cerr != hipSuccess) {
        convert_kernel<<<dim3(8192), dim3(256), 0, stream>>>(x, w_q, w_k, w_v, w_o, ws);
        qkv_gemm<<<dim3(32, 8), dim3(512), 0, stream>>>(x_bf, wq_bf, wk_bf, wv_bf,
                                                        s_q, s_k, s_v, b_q, b_k, b_v,
                                                        q_ws, k_ws, v_ws);
    }
    attn_kernel<<<dim3(16, 32), dim3(512), 0, stream>>>(q_ws, k_ws, v_ws, ctx_ws);
    o_gemm<<<dim3(32, 8), dim3(512), 0, stream>>>(ctx_ws, wo_bf, s_o, b_o, (float*)d_out);
}

// Round 14
// 191.203 us; speedup vs baseline: 1.4667x; 1.4667x over previous
//
#include <hip/hip_runtime.h>
#include <hip/hip_bf16.h>

typedef unsigned short u16;
typedef __bf16 bf16x8 __attribute__((ext_vector_type(8)));
typedef __bf16 bf16x4 __attribute__((ext_vector_type(4)));
typedef float f32x4 __attribute__((ext_vector_type(4)));
typedef unsigned short u16x8 __attribute__((ext_vector_type(8)));

// round-to-nearest-even fp32 -> bf16 (epilogue paths only)
__device__ inline u16 f2bf(float f) {
    union { float f; unsigned u; } v; v.f = f;
    unsigned r = v.u + 0x7fffu + ((v.u >> 16) & 1u);
    return (u16)(r >> 16);
}

// ---------------------------------------------------------------------------
// Convert x and 4 weights to bf16, contiguous in ws:
//   [x_bf 4194304][wq 1048576][wk][wv][wo]
// (R12 lesson: keep this a STANDALONE high-occupancy kernel — fusing it under
// a 128KB-LDS GEMM capped it at 8 waves/CU and it ran latency-bound at
// ~750 GB/s, 116 us. Separate: 8192 blocks, ~9 us.)
// ---------------------------------------------------------------------------
__global__ void convert_kernel(const float* __restrict__ x,
                               const float* __restrict__ wq, const float* __restrict__ wk,
                               const float* __restrict__ wv, const float* __restrict__ wo,
                               u16* __restrict__ dst) {
    long g = (long)blockIdx.x * blockDim.x + threadIdx.x;  // group of 4 elements
    const float* src; long base;
    const long GX = 1048576, GW = 262144;
    if (g < GX)            { src = x;  base = 0; }
    else if (g < GX + GW)  { src = wq; base = GX; }
    else if (g < GX + 2*GW){ src = wk; base = GX + GW; }
    else if (g < GX + 3*GW){ src = wv; base = GX + 2*GW; }
    else                   { src = wo; base = GX + 3*GW; }
    long rel = g - base;
    float4 v = reinterpret_cast<const float4*>(src)[rel];
    ushort4 o;
    o.x = f2bf(v.x); o.y = f2bf(v.y); o.z = f2bf(v.z); o.w = f2bf(v.w);
    reinterpret_cast<ushort4*>(dst)[g] = o;
}

// ---------------------------------------------------------------------------
// QKV projection, Z-FUSED (R10-verbatim — measured best). One block computes
// q, k AND v for its (t0, n0) tile; A staged once feeds 3 W-tiles. Grid
// (32,8) = 256 blocks = 1 block/CU, 8 waves, LDS 128 KB. Natural-order grid
// (R7 lesson: do NOT XCD-swizzle; round-robin already pins A-tiles per XCD).
//   q_ws/k_ws: [bh][s][64] bf16 (q pre-scaled by log2(e)/8)
//   v_ws:      [bh][64][s] bf16 (transposed for attention PV B-frags)
// ---------------------------------------------------------------------------
__global__ void __launch_bounds__(512)
qkv_gemm(const u16* __restrict__ x_bf,
         const u16* __restrict__ wq, const u16* __restrict__ wk, const u16* __restrict__ wv,
         const float* __restrict__ sq, const float* __restrict__ sk, const float* __restrict__ sv,
         const float* __restrict__ bq, const float* __restrict__ bk, const float* __restrict__ bv,
         u16* __restrict__ q_ws, u16* __restrict__ k_ws, u16* __restrict__ v_ws) {
    __shared__ __align__(16) u16 As[2][8192];       // [buf][128 rows x 64 els]
    __shared__ __align__(16) u16 Bs[2][3 * 8192];   // [buf][z][128 rows x 64 els]
    const int t0 = blockIdx.x * 128, n0 = blockIdx.y * 128;

    const int tid = threadIdx.x;
    const int wid = tid >> 6, lane = tid & 63, quad = lane >> 4, ln = lane & 15;
    const int wm = wid >> 2, wn = wid & 3;   // 2x4 wave grid, wave tile 64x32 per z

    // staging assignment (wave-uniform): waves 0-1 stage A, waves 2-7 stage B
    const bool stA = (wid < 2);
    const int zz = stA ? 0 : ((wid - 2) >> 1);
    const u16* Wz = (zz == 0) ? wq : (zz == 1) ? wk : wv;
    const u16* gbase = stA ? x_bf : Wz;
    const int r0 = stA ? t0 : n0;
    const int ccb = stA ? (wid * 8) : (((wid - 2) & 1) * 8);  // chunk base 0 or 8

    // per-lane source geometry: chunk = 8 rows x 128 B; lane fills 16 B
    const int lrow = lane >> 3;                       // row within chunk (0..7)
    const int sel  = 8 * ((lane & 7) ^ lrow);         // swizzled src col (els)

    f32x4 acc[3][4][2];
#pragma unroll
    for (int z = 0; z < 3; z++)
#pragma unroll
        for (int im = 0; im < 4; im++)
#pragma unroll
            for (int in = 0; in < 2; in++) acc[z][im][in] = (f32x4){0.f, 0.f, 0.f, 0.f};

#define QK_STAGE(buf, k0)                                                             \
    {                                                                                 \
        u16* dbase = stA ? &As[buf][0] : &Bs[buf][zz * 8192];                         \
        _Pragma("unroll")                                                             \
        for (int i = 0; i < 8; i++) {                                                 \
            int cc = ccb + i;                                                         \
            const u16* g = gbase + (long)(r0 + cc * 8 + lrow) * 1024 + (k0) + sel;    \
            __builtin_amdgcn_global_load_lds(                                         \
                (const __attribute__((address_space(1))) void*)g,                     \
                (__attribute__((address_space(3))) void*)(dbase + cc * 512), 16, 0, 0); \
        }                                                                             \
    }

    QK_STAGE(0, 0);
    __syncthreads();

    int cur = 0;
    for (int k0 = 0; k0 < 1024; k0 += 64) {
        if (k0 + 64 < 1024) QK_STAGE(cur ^ 1, k0 + 64);
        const char* Ac = (const char*)&As[cur][0];
        const char* Bc = (const char*)&Bs[cur][0];
#pragma unroll
        for (int ks = 0; ks < 2; ks++) {
            bf16x8 af[4];
#pragma unroll
            for (int im = 0; im < 4; im++) {
                int r = wm * 64 + im * 16 + ln;
                int byt = (r * 128 + ks * 64 + quad * 16) ^ ((r & 7) << 4);
                af[im] = *reinterpret_cast<const bf16x8*>(Ac + byt);
            }
            int rb = wn * 32 + ln;
#pragma unroll
            for (int z = 0; z < 3; z++) {
                bf16x8 b0, b1;
                {
                    int r = rb;
                    int byt = (r * 128 + ks * 64 + quad * 16) ^ ((r & 7) << 4);
                    b0 = *reinterpret_cast<const bf16x8*>(Bc + z * 16384 + byt);
                    r = rb + 16;
                    byt = (r * 128 + ks * 64 + quad * 16) ^ ((r & 7) << 4);
                    b1 = *reinterpret_cast<const bf16x8*>(Bc + z * 16384 + byt);
                }
                __builtin_amdgcn_s_setprio(1);
#pragma unroll
                for (int im = 0; im < 4; im++) {
                    acc[z][im][0] = __builtin_amdgcn_mfma_f32_16x16x32_bf16(af[im], b0, acc[z][im][0], 0, 0, 0);
                    acc[z][im][1] = __builtin_amdgcn_mfma_f32_16x16x32_bf16(af[im], b1, acc[z][im][1], 0, 0, 0);
                }
                __builtin_amdgcn_s_setprio(0);
            }
        }
        // single barrier: (a) protects buf[cur] reuse, (b) drains DMA into buf^1
        __syncthreads();
        cur ^= 1;
    }
#undef QK_STAGE

    // epilogue (R10 scalar form — R11's LDS-transpose variant was null)
    const float sq_ = sq[0] * 0.125f * 1.44269504088896f;  // softmax scale + log2e
    const float sk_ = sk[0];
    const float sv_ = sv[0];
#pragma unroll
    for (int z = 0; z < 3; z++) {
        u16* dst = (z == 0) ? q_ws : (z == 1) ? k_ws : v_ws;
        const float* bp = (z == 0) ? bq : (z == 1) ? bk : bv;
        const float s = (z == 0) ? sq_ : (z == 1) ? sk_ : sv_;
        const float be = (z == 0) ? 0.125f * 1.44269504088896f : 1.0f;
#pragma unroll
        for (int in = 0; in < 2; in++) {
            int col = n0 + wn * 32 + in * 16 + ln;
            float bias = bp[col] * be;
            int h = col >> 6, d = col & 63;
#pragma unroll
            for (int im = 0; im < 4; im++) {
                int rbase = t0 + wm * 64 + im * 16 + quad * 4;
#pragma unroll
                for (int j2 = 0; j2 < 4; j2++) {
                    int t = rbase + j2;
                    int b = t >> 11, ss = t & 2047;
                    int bh = b * 16 + h;
                    float val = acc[z][im][in][j2] * s + bias;
                    long idx = (z < 2) ? ((long)(bh * 2048 + ss) * 64 + d)
                                       : ((long)(bh * 64 + d) * 2048 + ss);
                    dst[idx] = f2bf(val);
                }
            }
        }
    }
}

// ---------------------------------------------------------------------------
// Attention. R14 (= R13 retry; prior round died to infra, no data): 256
// threads = 4 waves, each wave owns 32 q-rows (qt=0,1); block covers 128
// q-rows -> grid (16,32) = 512 blocks = 2 blocks/CU.
//
// WHY: attn is LDS-crossbar bound (R8 accounting: ~288 b128/CU/K-tile ≈ 3450
// cy vs ~3860 cy wall ≈ 90% busy). R9 amortized K/V fragment reads over 2x
// MFMA but moved to 1 block/CU and lost to the barrier convoy. This keeps
// R9's amortization (20 b128 / 36 MFMA = 0.56 vs R8's 1.0) AND R8's
// 2-blocks/CU convoy overlap. LDS 50 KB (Kb 16 + Vb 16 + Pt 18).
// Tradeoff accepted: 8 waves/CU instead of 16.
//
// XCD swizzle: XCD x pins 4 bh's K/V (2 MB, L2-resident), sweeps q-tiles
// (R7-measured: FETCH 69.7->12.3 MB). Schedule: DMA-before-compute into
// double-buffered swizzled-linear LDS, one barrier per K-tile; denominator
// on the MFMA pipe (acc_l = mfma(ap, ONES)); swapped QK^T (S^T = mfma(K,Q));
// exp2 with log2(e) folded into q at QKV time.
// ---------------------------------------------------------------------------
#define LDP 72

__global__ void __launch_bounds__(256)
attn_kernel(const u16* __restrict__ q_ws, const u16* __restrict__ k_ws,
            const u16* __restrict__ v_ws, u16* __restrict__ ctx) {
    __shared__ __align__(16) u16 Kb[2][4096];   // [buf][64 keys][64 d] swizzled
    __shared__ __align__(16) u16 Vb[2][4096];   // [buf][64 d][64 keys] swizzled
    __shared__ u16 Pt[128 * LDP];               // [q][key] exp(scores) bf16 (padded)

    const int tid = threadIdx.x;
    const int wid = tid >> 6, lane = tid & 63, quad = lane >> 4, ln = lane & 15;

    // XCD swizzle: XCD x pins 4 bh's K/V in its L2, sweeps q-tiles
    const int f   = blockIdx.x + 16 * blockIdx.y;
    const int xcd = f & 7, j = f >> 3;
    const int bh  = xcd * 4 + (j >> 4);
    const int q0  = (j & 15) * 128;

    const u16* qbase = q_ws + (long)bh * 2048 * 64;
    const u16* kbase = k_ws + (long)bh * 2048 * 64;
    const u16* vbase = v_ws + (long)bh * 64 * 2048;

    // staging geometry: 4 waves x 16B cover 32 rows per issue; 2 issues per
    // matrix. dest byte (i, wid, lane) = i*4096 + wid*1024 + lane*16 ->
    // row = i*32 + wid*8 + (lane>>3); row&7 = (lane>>3) (bases mult. of 8),
    // so one sel term serves both issues.
    const int srow = wid * 8 + (lane >> 3);                  // row 0..31 (issue 0)
    const int sel  = 8 * ((lane & 7) ^ ((lane >> 3) & 7));   // swizzled src col (els)
    // fragment-read XOR term (row ^= pattern depends only on ln&7)
    const int xr = (ln & 7) << 4;

    // Q fragments held in registers for the whole K loop (32 rows/wave)
    bf16x8 aq[2][2];
#pragma unroll
    for (int qt = 0; qt < 2; qt++)
#pragma unroll
        for (int ks = 0; ks < 2; ks++)
            aq[qt][ks] = *reinterpret_cast<const bf16x8*>(
                qbase + (long)(q0 + wid * 32 + qt * 16 + ln) * 64 + ks * 32 + quad * 8);

    // all-ones bf16 B-fragment for the denominator MFMA
    bf16x8 vones;
#pragma unroll
    for (int i = 0; i < 8; i++) vones[i] = (__bf16)1.0f;

    f32x4 acc_o[2][4];
    f32x4 acc_l[2];
#pragma unroll
    for (int qt = 0; qt < 2; qt++) {
        acc_l[qt] = (f32x4){0.f, 0.f, 0.f, 0.f};
#pragma unroll
        for (int dt = 0; dt < 4; dt++) acc_o[qt][dt] = (f32x4){0.f, 0.f, 0.f, 0.f};
    }

    // incremental DMA source pointers (issue 0 = rows 0..31; issue 1 adds a
    // 32-row offset: K rows stride 64 els, V rows stride 2048 els)
    const u16* kp = kbase + (long)srow * 64 + sel;     // advances by 64*64 els/tile
    const u16* vp = vbase + (long)srow * 2048 + sel;   // advances by 64 els/tile

#define ATTN_STAGE(buf)                                                                \
    {                                                                                  \
        __builtin_amdgcn_global_load_lds(                                              \
            (const __attribute__((address_space(1))) void*)kp,                         \
            (__attribute__((address_space(3))) void*)(&Kb[buf][wid * 512]), 16, 0, 0); \
        __builtin_amdgcn_global_load_lds(                                              \
            (const __attribute__((address_space(1))) void*)(kp + 32 * 64),             \
            (__attribute__((address_space(3))) void*)(&Kb[buf][2048 + wid * 512]), 16, 0, 0); \
        __builtin_amdgcn_global_load_lds(                                              \
            (const __attribute__((address_space(1))) void*)vp,                         \
            (__attribute__((address_space(3))) void*)(&Vb[buf][wid * 512]), 16, 0, 0); \
        __builtin_amdgcn_global_load_lds(                                              \
            (const __attribute__((address_space(1))) void*)(vp + 32 * 2048),           \
            (__attribute__((address_space(3))) void*)(&Vb[buf][2048 + wid * 512]), 16, 0, 0); \
    }

    // prologue: stage tile 0 into buf 0
    ATTN_STAGE(0);
    kp += 4096; vp += 64;
    __syncthreads();

    int cur = 0;
    for (int kt = 0; kt < 2048; kt += 64) {
        // issue next tile's DMA first; it flies under this tile's compute
        if (kt + 64 < 2048) {
            ATTN_STAGE(cur ^ 1);
            kp += 4096; vp += 64;
        }
        const char* Kc = (const char*)(&Kb[cur][0]);
        const char* Vc = (const char*)(&Vb[cur][0]);

        // S^T = K Q^T (swapped). Lane (quad,ln): q = ln, keys = k8*16+quad*4+j
        // K-frags a0/a1 shared across both qt sub-blocks (the amortization).
#pragma unroll
        for (int k8 = 0; k8 < 4; k8++) {
            bf16x8 a0 = *reinterpret_cast<const bf16x8*>(
                Kc + (k8 * 16 + ln) * 128 + ((quad * 16) ^ xr));
            bf16x8 a1 = *reinterpret_cast<const bf16x8*>(
                Kc + (k8 * 16 + ln) * 128 + ((64 + quad * 16) ^ xr));
#pragma unroll
            for (int qt = 0; qt < 2; qt++) {
                f32x4 t = (f32x4){0.f, 0.f, 0.f, 0.f};
                __builtin_amdgcn_s_setprio(1);
                t = __builtin_amdgcn_mfma_f32_16x16x32_bf16(a0, aq[qt][0], t, 0, 0, 0);
                t = __builtin_amdgcn_mfma_f32_16x16x32_bf16(a1, aq[qt][1], t, 0, 0, 0);
                __builtin_amdgcn_s_setprio(0);
                // bare v_exp_f32 (log2e folded into q); compiler-path bf16 casts
                __bf16 p0 = (__bf16)__builtin_amdgcn_exp2f(t[0]);
                __bf16 p1 = (__bf16)__builtin_amdgcn_exp2f(t[1]);
                __bf16 p2 = (__bf16)__builtin_amdgcn_exp2f(t[2]);
                __bf16 p3 = (__bf16)__builtin_amdgcn_exp2f(t[3]);
                *reinterpret_cast<bf16x4*>(
                    Pt + (wid * 32 + qt * 16 + ln) * LDP + k8 * 16 + quad * 4)
                    = (bf16x4){p0, p1, p2, p3};
            }
        }

        // O += P V ; l += P 1  (A-frag reads of Pt are wave-local rows;
        // V-frags bv0..bv3 shared across both qt sub-blocks)
#pragma unroll
        for (int step = 0; step < 2; step++) {
            bf16x8 ap0 = *reinterpret_cast<const bf16x8*>(
                Pt + (wid * 32 + ln) * LDP + step * 32 + quad * 8);
            bf16x8 ap1 = *reinterpret_cast<const bf16x8*>(
                Pt + (wid * 32 + 16 + ln) * LDP + step * 32 + quad * 8);
            bf16x8 bv0 = *reinterpret_cast<const bf16x8*>(
                Vc + (0 * 16 + ln) * 128 + ((step * 64 + quad * 16) ^ xr));
            bf16x8 bv1 = *reinterpret_cast<const bf16x8*>(
                Vc + (1 * 16 + ln) * 128 + ((step * 64 + quad * 16) ^ xr));
            bf16x8 bv2 = *reinterpret_cast<const bf16x8*>(
                Vc + (2 * 16 + ln) * 128 + ((step * 64 + quad * 16) ^ xr));
            bf16x8 bv3 = *reinterpret_cast<const bf16x8*>(
                Vc + (3 * 16 + ln) * 128 + ((step * 64 + quad * 16) ^ xr));
            __builtin_amdgcn_s_setprio(1);
            acc_o[0][0] = __builtin_amdgcn_mfma_f32_16x16x32_bf16(ap0, bv0, acc_o[0][0], 0, 0, 0);
            acc_o[0][1] = __builtin_amdgcn_mfma_f32_16x16x32_bf16(ap0, bv1, acc_o[0][1], 0, 0, 0);
            acc_o[0][2] = __builtin_amdgcn_mfma_f32_16x16x32_bf16(ap0, bv2, acc_o[0][2], 0, 0, 0);
            acc_o[0][3] = __builtin_amdgcn_mfma_f32_16x16x32_bf16(ap0, bv3, acc_o[0][3], 0, 0, 0);
            acc_l[0]    = __builtin_amdgcn_mfma_f32_16x16x32_bf16(ap0, vones, acc_l[0], 0, 0, 0);
            acc_o[1][0] = __builtin_amdgcn_mfma_f32_16x16x32_bf16(ap1, bv0, acc_o[1][0], 0, 0, 0);
            acc_o[1][1] = __builtin_amdgcn_mfma_f32_16x16x32_bf16(ap1, bv1, acc_o[1][1], 0, 0, 0);
            acc_o[1][2] = __builtin_amdgcn_mfma_f32_16x16x32_bf16(ap1, bv2, acc_o[1][2], 0, 0, 0);
            acc_o[1][3] = __builtin_amdgcn_mfma_f32_16x16x32_bf16(ap1, bv3, acc_o[1][3], 0, 0, 0);
            acc_l[1]    = __builtin_amdgcn_mfma_f32_16x16x32_bf16(ap1, vones, acc_l[1], 0, 0, 0);
            __builtin_amdgcn_s_setprio(0);
        }
        // single barrier per K-tile: orders (a) all reads of buf[cur] before it
        // is overwritten next iter, (b) drains this iter's DMA into buf[cur^1]
        __syncthreads();
        cur ^= 1;
    }
#undef ATTN_STAGE

    // write ctx [t][h*64+d] bf16; acc_l[qt][j] is the denominator for q-row
    // wid*32 + qt*16 + quad*4 + j (same row acc_o[qt][dt][j] holds)
    const int b = bh >> 4, h = bh & 15;
#pragma unroll
    for (int qt = 0; qt < 2; qt++) {
#pragma unroll
        for (int j2 = 0; j2 < 4; j2++) {
            float rinv = 1.0f / acc_l[qt][j2];
            int t = b * 2048 + q0 + wid * 32 + qt * 16 + quad * 4 + j2;
#pragma unroll
            for (int dt = 0; dt < 4; dt++) {
                float val = acc_o[qt][dt][j2] * rinv;
                ctx[(long)t * 1024 + h * 64 + dt * 16 + ln] = f2bf(val);
            }
        }
    }
}

// ---------------------------------------------------------------------------
// Output projection: d_out[t][o] = ctx @ wo^T * s_o + b_o  (fp32 out)
// (UNCHANGED — natural-order grid, 8-wave double-buffered single-barrier.)
// ---------------------------------------------------------------------------
__global__ void __launch_bounds__(512)
o_gemm(const u16* __restrict__ ctx, const u16* __restrict__ wo,
       const float* __restrict__ so, const float* __restrict__ bo,
       float* __restrict__ out) {
    __shared__ __align__(16) u16 As[2][128 * 64];
    __shared__ __align__(16) u16 Bs[2][128 * 64];
    const int tid = threadIdx.x;
    const int wid = tid >> 6, lane = tid & 63, quad = lane >> 4, ln = lane & 15;
    const int wm = wid >> 2, wn = wid & 3;   // 2x4 wave grid, wave tile 64x32
    const int t0 = blockIdx.x * 128, n0 = blockIdx.y * 128;

    // wave-uniform staging assignment: waves 0-3 -> A chunks, 4-7 -> B chunks
    const bool stA = (wid < 4);
    const u16* gbase = stA ? ctx : wo;
    const int r0 = stA ? t0 : n0;
    const int cbase = (wid & 3) * 4;         // 4 chunks of 1 KB per wave

    f32x4 acc[4][2];
#pragma unroll
    for (int im = 0; im < 4; im++)
#pragma unroll
        for (int in = 0; in < 2; in++) acc[im][in] = (f32x4){0.f, 0.f, 0.f, 0.f};

    // per-lane staging source geometry (swizzled global source, linear LDS)
    const int sb   = cbase * 1024 + lane * 16;
    const int srow = sb >> 7;
    const int scb  = (sb & 127) ^ ((srow & 7) << 4);

#define O_STAGE(buf, k0)                                                              \
    {                                                                                 \
        const u16* g = gbase + (long)(r0 + srow) * 1024 + (k0) + (scb >> 1);          \
        u16* d = (stA ? &As[buf][0] : &Bs[buf][0]) + cbase * 512;                     \
        _Pragma("unroll")                                                             \
        for (int i = 0; i < 4; i++) {                                                 \
            __builtin_amdgcn_global_load_lds(                                         \
                (const __attribute__((address_space(1))) void*)(g + (long)i * 8 * 1024), \
                (__attribute__((address_space(3))) void*)(d + i * 512), 16, 0, 0);    \
        }                                                                             \
    }

    O_STAGE(0, 0);
    __syncthreads();

    int cur = 0;
    for (int k0 = 0; k0 < 1024; k0 += 64) {
        if (k0 + 64 < 1024) O_STAGE(cur ^ 1, k0 + 64);
        const char* Ac = (const char*)&As[cur][0];
        const char* Bc = (const char*)&Bs[cur][0];
#pragma unroll
        for (int ks = 0; ks < 2; ks++) {
            bf16x8 af[4], bfr[2];
#pragma unroll
            for (int im = 0; im < 4; im++) {
                int r = wm * 64 + im * 16 + ln;
                int byt = (r * 128 + ks * 64 + quad * 16) ^ ((r & 7) << 4);
                af[im] = *reinterpret_cast<const bf16x8*>(Ac + byt);
            }
#pragma unroll
            for (int in = 0; in < 2; in++) {
                int r = wn * 32 + in * 16 + ln;
                int byt = (r * 128 + ks * 64 + quad * 16) ^ ((r & 7) << 4);
                bfr[in] = *reinterpret_cast<const bf16x8*>(Bc + byt);
            }
#pragma unroll
            for (int im = 0; im < 4; im++)
#pragma unroll
                for (int in = 0; in < 2; in++)
                    acc[im][in] = __builtin_amdgcn_mfma_f32_16x16x32_bf16(af[im], bfr[in], acc[im][in], 0, 0, 0);
        }
        // single barrier: (a) protects buf[cur] reuse, (b) drains DMA into buf^1
        __syncthreads();
        cur ^= 1;
    }
#undef O_STAGE

    const float s = so[0];
#pragma unroll
    for (int in = 0; in < 2; in++) {
        int col = n0 + wn * 32 + in * 16 + ln;
        float bias = bo[col];
#pragma unroll
        for (int im = 0; im < 4; im++) {
            int rbase = t0 + wm * 64 + im * 16 + quad * 4;
#pragma unroll
            for (int j2 = 0; j2 < 4; j2++)
                out[(long)(rbase + j2) * 1024 + col] = acc[im][in][j2] * s + bias;
        }
    }
}

// ---------------------------------------------------------------------------
extern "C" void kernel_launch(void* const* d_in, const int* in_sizes, int n_in,
                              void* d_out, int out_size, void* d_ws, size_t ws_size,
                              hipStream_t stream) {
    const float* x   = (const float*)d_in[0];
    const float* w_q = (const float*)d_in[1];
    const float* s_q = (const float*)d_in[2];
    const float* b_q = (const float*)d_in[3];
    const float* w_k = (const float*)d_in[4];
    const float* s_k = (const float*)d_in[5];
    const float* b_k = (const float*)d_in[6];
    const float* w_v = (const float*)d_in[7];
    const float* s_v = (const float*)d_in[8];
    const float* b_v = (const float*)d_in[9];
    const float* w_o = (const float*)d_in[10];
    const float* s_o = (const float*)d_in[11];
    const float* b_o = (const float*)d_in[12];

    if (ws_size < (size_t)50331648) return;  // need 48 MB of scratch

    u16* ws     = (u16*)d_ws;
    u16* x_bf   = ws;                    // 4096*1024
    u16* wq_bf  = x_bf  + 4194304;       // 1024*1024 each
    u16* wk_bf  = wq_bf + 1048576;
    u16* wv_bf  = wk_bf + 1048576;
    u16* wo_bf  = wv_bf + 1048576;
    u16* q_ws   = wo_bf + 1048576;       // [32 bh][2048 s][64 d]
    u16* k_ws   = q_ws  + 4194304;
    u16* v_ws   = k_ws  + 4194304;       // [32 bh][64 d][2048 s]
    u16* ctx_ws = v_ws  + 4194304;       // [4096 t][1024]

    convert_kernel<<<dim3(8192), dim3(256), 0, stream>>>(x, w_q, w_k, w_v, w_o, ws);
    qkv_gemm<<<dim3(32, 8), dim3(512), 0, stream>>>(x_bf, wq_bf, wk_bf, wv_bf,
                                                    s_q, s_k, s_v, b_q, b_k, b_v,
                                                    q_ws, k_ws, v_ws);
    attn_kernel<<<dim3(16, 32), dim3(256), 0, stream>>>(q_ws, k_ws, v_ws, ctx_ws);
    o_gemm<<<dim3(32, 8), dim3(512), 0, stream>>>(ctx_ws, wo_bf, s_o, b_o, (float*)d_out);
}

// Round 15
// 185.253 us; speedup vs baseline: 1.5138x; 1.0321x over previous
//
#include <hip/hip_runtime.h>
#include <hip/hip_bf16.h>

typedef unsigned short u16;
typedef __bf16 bf16x8 __attribute__((ext_vector_type(8)));
typedef __bf16 bf16x4 __attribute__((ext_vector_type(4)));
typedef float f32x4 __attribute__((ext_vector_type(4)));
typedef unsigned short u16x8 __attribute__((ext_vector_type(8)));

// round-to-nearest-even fp32 -> bf16 (epilogue paths only)
__device__ inline u16 f2bf(float f) {
    union { float f; unsigned u; } v; v.f = f;
    unsigned r = v.u + 0x7fffu + ((v.u >> 16) & 1u);
    return (u16)(r >> 16);
}

// ---------------------------------------------------------------------------
// Convert x and 4 weights to bf16, contiguous in ws:
//   [x_bf 4194304][wq 1048576][wk][wv][wo]
// (R12 lesson: keep standalone/high-occupancy — fusing under a 128KB-LDS GEMM
// ran latency-bound at 8 waves/CU, 116 us vs ~9 us here.)
// ---------------------------------------------------------------------------
__global__ void convert_kernel(const float* __restrict__ x,
                               const float* __restrict__ wq, const float* __restrict__ wk,
                               const float* __restrict__ wv, const float* __restrict__ wo,
                               u16* __restrict__ dst) {
    long g = (long)blockIdx.x * blockDim.x + threadIdx.x;  // group of 4 elements
    const float* src; long base;
    const long GX = 1048576, GW = 262144;
    if (g < GX)            { src = x;  base = 0; }
    else if (g < GX + GW)  { src = wq; base = GX; }
    else if (g < GX + 2*GW){ src = wk; base = GX + GW; }
    else if (g < GX + 3*GW){ src = wv; base = GX + 2*GW; }
    else                   { src = wo; base = GX + 3*GW; }
    long rel = g - base;
    float4 v = reinterpret_cast<const float4*>(src)[rel];
    ushort4 o;
    o.x = f2bf(v.x); o.y = f2bf(v.y); o.z = f2bf(v.z); o.w = f2bf(v.w);
    reinterpret_cast<ushort4*>(dst)[g] = o;
}

// ---------------------------------------------------------------------------
// QKV projection, Z-FUSED (R10 measured-best). One block computes q, k AND v
// for its (t0, n0) tile; A staged once feeds 3 W-tiles. Grid (32,8) = 256
// blocks = 1 block/CU, 8 waves, LDS 128 KB. Natural-order grid (R7 lesson:
// do NOT XCD-swizzle; round-robin already pins A-tiles per XCD).
// R11's LDS-transpose epilogue was null; scalar epilogue kept.
//   q_ws/k_ws: [bh][s][64] bf16 (q pre-scaled by log2(e)/8)
//   v_ws:      [bh][64][s] bf16 (transposed for attention PV B-frags)
// ---------------------------------------------------------------------------
__global__ void __launch_bounds__(512)
qkv_gemm(const u16* __restrict__ x_bf,
         const u16* __restrict__ wq, const u16* __restrict__ wk, const u16* __restrict__ wv,
         const float* __restrict__ sq, const float* __restrict__ sk, const float* __restrict__ sv,
         const float* __restrict__ bq, const float* __restrict__ bk, const float* __restrict__ bv,
         u16* __restrict__ q_ws, u16* __restrict__ k_ws, u16* __restrict__ v_ws) {
    __shared__ __align__(16) u16 As[2][8192];       // [buf][128 rows x 64 els]
    __shared__ __align__(16) u16 Bs[2][3 * 8192];   // [buf][z][128 rows x 64 els]
    const int t0 = blockIdx.x * 128, n0 = blockIdx.y * 128;

    const int tid = threadIdx.x;
    const int wid = tid >> 6, lane = tid & 63, quad = lane >> 4, ln = lane & 15;
    const int wm = wid >> 2, wn = wid & 3;   // 2x4 wave grid, wave tile 64x32 per z

    // staging assignment (wave-uniform): waves 0-1 stage A, waves 2-7 stage B
    const bool stA = (wid < 2);
    const int zz = stA ? 0 : ((wid - 2) >> 1);
    const u16* Wz = (zz == 0) ? wq : (zz == 1) ? wk : wv;
    const u16* gbase = stA ? x_bf : Wz;
    const int r0 = stA ? t0 : n0;
    const int ccb = stA ? (wid * 8) : (((wid - 2) & 1) * 8);  // chunk base 0 or 8

    // per-lane source geometry: chunk = 8 rows x 128 B; lane fills 16 B
    const int lrow = lane >> 3;                       // row within chunk (0..7)
    const int sel  = 8 * ((lane & 7) ^ lrow);         // swizzled src col (els)

    f32x4 acc[3][4][2];
#pragma unroll
    for (int z = 0; z < 3; z++)
#pragma unroll
        for (int im = 0; im < 4; im++)
#pragma unroll
            for (int in = 0; in < 2; in++) acc[z][im][in] = (f32x4){0.f, 0.f, 0.f, 0.f};

#define QK_STAGE(buf, k0)                                                             \
    {                                                                                 \
        u16* dbase = stA ? &As[buf][0] : &Bs[buf][zz * 8192];                         \
        _Pragma("unroll")                                                             \
        for (int i = 0; i < 8; i++) {                                                 \
            int cc = ccb + i;                                                         \
            const u16* g = gbase + (long)(r0 + cc * 8 + lrow) * 1024 + (k0) + sel;    \
            __builtin_amdgcn_global_load_lds(                                         \
                (const __attribute__((address_space(1))) void*)g,                     \
                (__attribute__((address_space(3))) void*)(dbase + cc * 512), 16, 0, 0); \
        }                                                                             \
    }

    QK_STAGE(0, 0);
    __syncthreads();

    int cur = 0;
    for (int k0 = 0; k0 < 1024; k0 += 64) {
        if (k0 + 64 < 1024) QK_STAGE(cur ^ 1, k0 + 64);
        const char* Ac = (const char*)&As[cur][0];
        const char* Bc = (const char*)&Bs[cur][0];
#pragma unroll
        for (int ks = 0; ks < 2; ks++) {
            bf16x8 af[4];
#pragma unroll
            for (int im = 0; im < 4; im++) {
                int r = wm * 64 + im * 16 + ln;
                int byt = (r * 128 + ks * 64 + quad * 16) ^ ((r & 7) << 4);
                af[im] = *reinterpret_cast<const bf16x8*>(Ac + byt);
            }
            int rb = wn * 32 + ln;
#pragma unroll
            for (int z = 0; z < 3; z++) {
                bf16x8 b0, b1;
                {
                    int r = rb;
                    int byt = (r * 128 + ks * 64 + quad * 16) ^ ((r & 7) << 4);
                    b0 = *reinterpret_cast<const bf16x8*>(Bc + z * 16384 + byt);
                    r = rb + 16;
                    byt = (r * 128 + ks * 64 + quad * 16) ^ ((r & 7) << 4);
                    b1 = *reinterpret_cast<const bf16x8*>(Bc + z * 16384 + byt);
                }
                __builtin_amdgcn_s_setprio(1);
#pragma unroll
                for (int im = 0; im < 4; im++) {
                    acc[z][im][0] = __builtin_amdgcn_mfma_f32_16x16x32_bf16(af[im], b0, acc[z][im][0], 0, 0, 0);
                    acc[z][im][1] = __builtin_amdgcn_mfma_f32_16x16x32_bf16(af[im], b1, acc[z][im][1], 0, 0, 0);
                }
                __builtin_amdgcn_s_setprio(0);
            }
        }
        // single barrier: (a) protects buf[cur] reuse, (b) drains DMA into buf^1
        __syncthreads();
        cur ^= 1;
    }
#undef QK_STAGE

    // epilogue (R10 scalar form — measured best)
    const float sq_ = sq[0] * 0.125f * 1.44269504088896f;  // softmax scale + log2e
    const float sk_ = sk[0];
    const float sv_ = sv[0];
#pragma unroll
    for (int z = 0; z < 3; z++) {
        u16* dst = (z == 0) ? q_ws : (z == 1) ? k_ws : v_ws;
        const float* bp = (z == 0) ? bq : (z == 1) ? bk : bv;
        const float s = (z == 0) ? sq_ : (z == 1) ? sk_ : sv_;
        const float be = (z == 0) ? 0.125f * 1.44269504088896f : 1.0f;
#pragma unroll
        for (int in = 0; in < 2; in++) {
            int col = n0 + wn * 32 + in * 16 + ln;
            float bias = bp[col] * be;
            int h = col >> 6, d = col & 63;
#pragma unroll
            for (int im = 0; im < 4; im++) {
                int rbase = t0 + wm * 64 + im * 16 + quad * 4;
#pragma unroll
                for (int j2 = 0; j2 < 4; j2++) {
                    int t = rbase + j2;
                    int b = t >> 11, ss = t & 2047;
                    int bh = b * 16 + h;
                    float val = acc[z][im][in][j2] * s + bias;
                    long idx = (z < 2) ? ((long)(bh * 2048 + ss) * 64 + d)
                                       : ((long)(bh * 64 + d) * 2048 + ss);
                    dst[idx] = f2bf(val);
                }
            }
        }
    }
}

// ---------------------------------------------------------------------------
// Attention: per (q-tile of 128, bh). 512 threads = 8 waves, each wave owns
// 16 q-rows — the proven local optimum across the occupancy sweep:
// {4w/32row 2blk: 54.7 (R14), 8w/32row 1blk: 55.0 (R9), 8w/16row 2blk: 51.5}.
// LDS-amortization theory refuted twice: attn is latency/issue bound at
// 16 waves/CU, not LDS-crossbar bound.
//
// XCD swizzle: XCD x pins 4 bh's K/V (2 MB, L2-resident), sweeps q-tiles
// (R7-measured: FETCH 69.7->12.3 MB). Schedule: DMA-before-compute into
// double-buffered swizzled-linear LDS, one barrier per K-tile; denominator
// on the MFMA pipe (acc_l = mfma(ap, ONES)); swapped QK^T (S^T = mfma(K,Q));
// exp2 with log2(e) folded into q at QKV time.
// ---------------------------------------------------------------------------
#define LDP 72

__global__ void __launch_bounds__(512)
attn_kernel(const u16* __restrict__ q_ws, const u16* __restrict__ k_ws,
            const u16* __restrict__ v_ws, u16* __restrict__ ctx) {
    __shared__ __align__(16) u16 Kb[2][4096];   // [buf][64 keys][64 d] swizzled
    __shared__ __align__(16) u16 Vb[2][4096];   // [buf][64 d][64 keys] swizzled
    __shared__ u16 Pt[128 * LDP];               // [q][key] exp(scores) bf16 (padded)

    const int tid = threadIdx.x;
    const int wid = tid >> 6, lane = tid & 63, quad = lane >> 4, ln = lane & 15;

    // XCD swizzle: XCD x pins 4 bh's K/V in its L2, sweeps q-tiles
    const int f   = blockIdx.x + 16 * blockIdx.y;
    const int xcd = f & 7, j = f >> 3;
    const int bh  = xcd * 4 + (j >> 4);
    const int q0  = (j & 15) * 128;

    const u16* qbase = q_ws + (long)bh * 2048 * 64;
    const u16* kbase = k_ws + (long)bh * 2048 * 64;
    const u16* vbase = v_ws + (long)bh * 64 * 2048;

    // staging geometry: wave w fills LDS bytes [w*1024 + lane*16)
    const int srow = wid * 8 + (lane >> 3);                  // tile row 0..63
    const int sel  = 8 * ((lane & 7) ^ ((lane >> 3) & 7));   // swizzled src col (els)
    // fragment-read XOR term (row ^= pattern depends only on ln&7)
    const int xr = (ln & 7) << 4;

    // Q fragments held in registers for the whole K loop
    bf16x8 aq[2];
#pragma unroll
    for (int ks = 0; ks < 2; ks++)
        aq[ks] = *reinterpret_cast<const bf16x8*>(
            qbase + (long)(q0 + wid * 16 + ln) * 64 + ks * 32 + quad * 8);

    // all-ones bf16 B-fragment for the denominator MFMA
    bf16x8 vones;
#pragma unroll
    for (int i = 0; i < 8; i++) vones[i] = (__bf16)1.0f;

    f32x4 acc_o[4];
    f32x4 acc_l = (f32x4){0.f, 0.f, 0.f, 0.f};
#pragma unroll
    for (int dt = 0; dt < 4; dt++) acc_o[dt] = (f32x4){0.f, 0.f, 0.f, 0.f};

    // incremental DMA source pointers (avoids per-iter 64-bit addr rebuild)
    const u16* kp = kbase + (long)srow * 64 + sel;     // advances by 64*64 els/tile
    const u16* vp = vbase + (long)srow * 2048 + sel;   // advances by 64 els/tile

    // prologue: stage tile 0 into buf 0
    __builtin_amdgcn_global_load_lds((const __attribute__((address_space(1))) void*)kp,
                                     (__attribute__((address_space(3))) void*)(&Kb[0][wid * 512]),
                                     16, 0, 0);
    __builtin_amdgcn_global_load_lds((const __attribute__((address_space(1))) void*)vp,
                                     (__attribute__((address_space(3))) void*)(&Vb[0][wid * 512]),
                                     16, 0, 0);
    kp += 4096; vp += 64;
    __syncthreads();

    int cur = 0;
    for (int kt = 0; kt < 2048; kt += 64) {
        // issue next tile's DMA first; it flies under this tile's compute
        if (kt + 64 < 2048) {
            __builtin_amdgcn_global_load_lds((const __attribute__((address_space(1))) void*)kp,
                                             (__attribute__((address_space(3))) void*)(&Kb[cur ^ 1][wid * 512]),
                                             16, 0, 0);
            __builtin_amdgcn_global_load_lds((const __attribute__((address_space(1))) void*)vp,
                                             (__attribute__((address_space(3))) void*)(&Vb[cur ^ 1][wid * 512]),
                                             16, 0, 0);
            kp += 4096; vp += 64;
        }
        const char* Kc = (const char*)(&Kb[cur][0]);
        const char* Vc = (const char*)(&Vb[cur][0]);

        // S^T = K Q^T (swapped). Lane (quad,ln): q = ln, keys = k8*16+quad*4+j
#pragma unroll
        for (int k8 = 0; k8 < 4; k8++) {
            bf16x8 a0 = *reinterpret_cast<const bf16x8*>(
                Kc + (k8 * 16 + ln) * 128 + ((quad * 16) ^ xr));
            bf16x8 a1 = *reinterpret_cast<const bf16x8*>(
                Kc + (k8 * 16 + ln) * 128 + ((64 + quad * 16) ^ xr));
            f32x4 t = (f32x4){0.f, 0.f, 0.f, 0.f};
            __builtin_amdgcn_s_setprio(1);
            t = __builtin_amdgcn_mfma_f32_16x16x32_bf16(a0, aq[0], t, 0, 0, 0);
            t = __builtin_amdgcn_mfma_f32_16x16x32_bf16(a1, aq[1], t, 0, 0, 0);
            __builtin_amdgcn_s_setprio(0);
            // bare v_exp_f32 (log2e folded into q); compiler-path bf16 casts
            __bf16 p0 = (__bf16)__builtin_amdgcn_exp2f(t[0]);
            __bf16 p1 = (__bf16)__builtin_amdgcn_exp2f(t[1]);
            __bf16 p2 = (__bf16)__builtin_amdgcn_exp2f(t[2]);
            __bf16 p3 = (__bf16)__builtin_amdgcn_exp2f(t[3]);
            *reinterpret_cast<bf16x4*>(Pt + (wid * 16 + ln) * LDP + k8 * 16 + quad * 4)
                = (bf16x4){p0, p1, p2, p3};
        }

        // O += P V ; l += P 1  (A-frag reads of Pt are wave-local rows)
#pragma unroll
        for (int step = 0; step < 2; step++) {
            bf16x8 ap = *reinterpret_cast<const bf16x8*>(
                Pt + (wid * 16 + ln) * LDP + step * 32 + quad * 8);
            bf16x8 bv0 = *reinterpret_cast<const bf16x8*>(
                Vc + (0 * 16 + ln) * 128 + ((step * 64 + quad * 16) ^ xr));
            bf16x8 bv1 = *reinterpret_cast<const bf16x8*>(
                Vc + (1 * 16 + ln) * 128 + ((step * 64 + quad * 16) ^ xr));
            bf16x8 bv2 = *reinterpret_cast<const bf16x8*>(
                Vc + (2 * 16 + ln) * 128 + ((step * 64 + quad * 16) ^ xr));
            bf16x8 bv3 = *reinterpret_cast<const bf16x8*>(
                Vc + (3 * 16 + ln) * 128 + ((step * 64 + quad * 16) ^ xr));
            __builtin_amdgcn_s_setprio(1);
            acc_o[0] = __builtin_amdgcn_mfma_f32_16x16x32_bf16(ap, bv0, acc_o[0], 0, 0, 0);
            acc_o[1] = __builtin_amdgcn_mfma_f32_16x16x32_bf16(ap, bv1, acc_o[1], 0, 0, 0);
            acc_o[2] = __builtin_amdgcn_mfma_f32_16x16x32_bf16(ap, bv2, acc_o[2], 0, 0, 0);
            acc_o[3] = __builtin_amdgcn_mfma_f32_16x16x32_bf16(ap, bv3, acc_o[3], 0, 0, 0);
            acc_l    = __builtin_amdgcn_mfma_f32_16x16x32_bf16(ap, vones, acc_l, 0, 0, 0);
            __builtin_amdgcn_s_setprio(0);
        }
        // single barrier per K-tile: orders (a) all reads of buf[cur] before it
        // is overwritten next iter, (b) drains this iter's DMA into buf[cur^1]
        __syncthreads();
        cur ^= 1;
    }

    // write ctx [t][h*64+d] bf16; acc_l[j] is the denominator for q-row
    // wid*16 + quad*4 + j (same row acc_o[dt][j] holds) — no shuffle needed
    const int b = bh >> 4, h = bh & 15;
#pragma unroll
    for (int j2 = 0; j2 < 4; j2++) {
        float rinv = 1.0f / acc_l[j2];
        int t = b * 2048 + q0 + wid * 16 + quad * 4 + j2;
#pragma unroll
        for (int dt = 0; dt < 4; dt++) {
            float val = acc_o[dt][j2] * rinv;
            ctx[(long)t * 1024 + h * 64 + dt * 16 + ln] = f2bf(val);
        }
    }
}

// ---------------------------------------------------------------------------
// Output projection: d_out[t][o] = ctx @ wo^T * s_o + b_o  (fp32 out)
// (R5 measured-best — natural-order grid, 8-wave double-buffered.)
// ---------------------------------------------------------------------------
__global__ void __launch_bounds__(512)
o_gemm(const u16* __restrict__ ctx, const u16* __restrict__ wo,
       const float* __restrict__ so, const float* __restrict__ bo,
       float* __restrict__ out) {
    __shared__ __align__(16) u16 As[2][128 * 64];
    __shared__ __align__(16) u16 Bs[2][128 * 64];
    const int tid = threadIdx.x;
    const int wid = tid >> 6, lane = tid & 63, quad = lane >> 4, ln = lane & 15;
    const int wm = wid >> 2, wn = wid & 3;   // 2x4 wave grid, wave tile 64x32
    const int t0 = blockIdx.x * 128, n0 = blockIdx.y * 128;

    // wave-uniform staging assignment: waves 0-3 -> A chunks, 4-7 -> B chunks
    const bool stA = (wid < 4);
    const u16* gbase = stA ? ctx : wo;
    const int r0 = stA ? t0 : n0;
    const int cbase = (wid & 3) * 4;         // 4 chunks of 1 KB per wave

    f32x4 acc[4][2];
#pragma unroll
    for (int im = 0; im < 4; im++)
#pragma unroll
        for (int in = 0; in < 2; in++) acc[im][in] = (f32x4){0.f, 0.f, 0.f, 0.f};

    // per-lane staging source geometry (swizzled global source, linear LDS)
    const int sb   = cbase * 1024 + lane * 16;
    const int srow = sb >> 7;
    const int scb  = (sb & 127) ^ ((srow & 7) << 4);

#define O_STAGE(buf, k0)                                                              \
    {                                                                                 \
        const u16* g = gbase + (long)(r0 + srow) * 1024 + (k0) + (scb >> 1);          \
        u16* d = (stA ? &As[buf][0] : &Bs[buf][0]) + cbase * 512;                     \
        _Pragma("unroll")                                                             \
        for (int i = 0; i < 4; i++) {                                                 \
            __builtin_amdgcn_global_load_lds(                                         \
                (const __attribute__((address_space(1))) void*)(g + (long)i * 8 * 1024), \
                (__attribute__((address_space(3))) void*)(d + i * 512), 16, 0, 0);    \
        }                                                                             \
    }

    O_STAGE(0, 0);
    __syncthreads();

    int cur = 0;
    for (int k0 = 0; k0 < 1024; k0 += 64) {
        if (k0 + 64 < 1024) O_STAGE(cur ^ 1, k0 + 64);
        const char* Ac = (const char*)&As[cur][0];
        const char* Bc = (const char*)&Bs[cur][0];
#pragma unroll
        for (int ks = 0; ks < 2; ks++) {
            bf16x8 af[4], bfr[2];
#pragma unroll
            for (int im = 0; im < 4; im++) {
                int r = wm * 64 + im * 16 + ln;
                int byt = (r * 128 + ks * 64 + quad * 16) ^ ((r & 7) << 4);
                af[im] = *reinterpret_cast<const bf16x8*>(Ac + byt);
            }
#pragma unroll
            for (int in = 0; in < 2; in++) {
                int r = wn * 32 + in * 16 + ln;
                int byt = (r * 128 + ks * 64 + quad * 16) ^ ((r & 7) << 4);
                bfr[in] = *reinterpret_cast<const bf16x8*>(Bc + byt);
            }
#pragma unroll
            for (int im = 0; im < 4; im++)
#pragma unroll
                for (int in = 0; in < 2; in++)
                    acc[im][in] = __builtin_amdgcn_mfma_f32_16x16x32_bf16(af[im], bfr[in], acc[im][in], 0, 0, 0);
        }
        // single barrier: (a) protects buf[cur] reuse, (b) drains DMA into buf^1
        __syncthreads();
        cur ^= 1;
    }
#undef O_STAGE

    const float s = so[0];
#pragma unroll
    for (int in = 0; in < 2; in++) {
        int col = n0 + wn * 32 + in * 16 + ln;
        float bias = bo[col];
#pragma unroll
        for (int im = 0; im < 4; im++) {
            int rbase = t0 + wm * 64 + im * 16 + quad * 4;
#pragma unroll
            for (int j2 = 0; j2 < 4; j2++)
                out[(long)(rbase + j2) * 1024 + col] = acc[im][in][j2] * s + bias;
        }
    }
}

// ---------------------------------------------------------------------------
extern "C" void kernel_launch(void* const* d_in, const int* in_sizes, int n_in,
                              void* d_out, int out_size, void* d_ws, size_t ws_size,
                              hipStream_t stream) {
    const float* x   = (const float*)d_in[0];
    const float* w_q = (const float*)d_in[1];
    const float* s_q = (const float*)d_in[2];
    const float* b_q = (const float*)d_in[3];
    const float* w_k = (const float*)d_in[4];
    const float* s_k = (const float*)d_in[5];
    const float* b_k = (const float*)d_in[6];
    const float* w_v = (const float*)d_in[7];
    const float* s_v = (const float*)d_in[8];
    const float* b_v = (const float*)d_in[9];
    const float* w_o = (const float*)d_in[10];
    const float* s_o = (const float*)d_in[11];
    const float* b_o = (const float*)d_in[12];

    if (ws_size < (size_t)50331648) return;  // need 48 MB of scratch

    u16* ws     = (u16*)d_ws;
    u16* x_bf   = ws;                    // 4096*1024
    u16* wq_bf  = x_bf  + 4194304;       // 1024*1024 each
    u16* wk_bf  = wq_bf + 1048576;
    u16* wv_bf  = wk_bf + 1048576;
    u16* wo_bf  = wv_bf + 1048576;
    u16* q_ws   = wo_bf + 1048576;       // [32 bh][2048 s][64 d]
    u16* k_ws   = q_ws  + 4194304;
    u16* v_ws   = k_ws  + 4194304;       // [32 bh][64 d][2048 s]
    u16* ctx_ws = v_ws  + 4194304;       // [4096 t][1024]

    convert_kernel<<<dim3(8192), dim3(256), 0, stream>>>(x, w_q, w_k, w_v, w_o, ws);
    qkv_gemm<<<dim3(32, 8), dim3(512), 0, stream>>>(x_bf, wq_bf, wk_bf, wv_bf,
                                                    s_q, s_k, s_v, b_q, b_k, b_v,
                                                    q_ws, k_ws, v_ws);
    attn_kernel<<<dim3(16, 32), dim3(512), 0, stream>>>(q_ws, k_ws, v_ws, ctx_ws);
    o_gemm<<<dim3(32, 8), dim3(512), 0, stream>>>(ctx_ws, wo_bf, s_o, b_o, (float*)d_out);
}